// Round 3
// baseline (474.778 us; speedup 1.0000x reference)
//
#include <hip/hip_runtime.h>

// PLIF forward scan: v = beta*v + x_t; s = (v-1 >= 0); v *= (1-s)
// T=32 sequential in registers; B*N lanes fully parallel.
// R1 post-mortem: VGPR=28 => only ~1 load in flight/thread, latency-bound at
// 2.8 TB/s. Fix: 4-deep explicit prefetch ring (4 outstanding dwordx4 loads)
// + non-temporal stores (out is write-once; stop dirtying L2/L3 and evicting
// x lines from the 256 MiB L3 that currently absorbs ~half the fetch).
// R2: __builtin_nontemporal_store needs a native vector type, not HIP float4.

#define T_STEPS 32
#define PF 4  // prefetch depth (must divide T_STEPS)

typedef float vfloat4 __attribute__((ext_vector_type(4)));

__global__ __launch_bounds__(256) void plif_fwd_kernel(
    const vfloat4* __restrict__ x, const float* __restrict__ beta_raw,
    vfloat4* __restrict__ out, int bn4)
{
    int i = blockIdx.x * blockDim.x + threadIdx.x;
    if (i >= bn4) return;

    // beta = sigmoid(beta_raw); precise expf to match reference trajectory
    float beta = 1.0f / (1.0f + expf(-beta_raw[0]));

    vfloat4 v = (vfloat4)(0.0f, 0.0f, 0.0f, 0.0f);

    // Prime the ring: 4 independent loads in flight before any compute.
    vfloat4 buf[PF];
    #pragma unroll
    for (int k = 0; k < PF; ++k) buf[k] = x[i + k * bn4];

    #pragma unroll
    for (int t = 0; t < T_STEPS; ++t) {
        vfloat4 xt = buf[t % PF];               // waits only on this slot's load
        if (t + PF < T_STEPS)
            buf[t % PF] = x[i + (t + PF) * bn4];  // refill: keep 4 in flight

        // v = beta*v + x_t  -- separate mul/add rounding (no fma contraction),
        // matching XLA's non-contracted mul+add HLO ops.
        vfloat4 s;
        #pragma unroll
        for (int c = 0; c < 4; ++c) {
            v[c] = __fadd_rn(__fmul_rn(beta, v[c]), xt[c]);
            // s = Heaviside(v - 1), reference op order: (v - one) >= 0
            s[c] = (__fadd_rn(v[c], -1.0f) >= 0.0f) ? 1.0f : 0.0f;
            // hard reset: v = v * (1 - s); exact since s in {0,1}
            v[c] *= (1.0f - s[c]);
        }

        // Non-temporal: out is write-once, never re-read by this launch.
        __builtin_nontemporal_store(s, &out[i + t * bn4]);
    }
}

extern "C" void kernel_launch(void* const* d_in, const int* in_sizes, int n_in,
                              void* d_out, int out_size, void* d_ws, size_t ws_size,
                              hipStream_t stream) {
    const float* x        = (const float*)d_in[0];
    const float* beta_raw = (const float*)d_in[1];
    float* out            = (float*)d_out;

    int total = in_sizes[0];        // T*B*N = 67,108,864
    int bn    = total / T_STEPS;    // B*N   =  2,097,152
    int bn4   = bn / 4;             // float4 lanes = 524,288

    dim3 block(256);
    dim3 grid((bn4 + block.x - 1) / block.x);
    plif_fwd_kernel<<<grid, block, 0, stream>>>(
        (const vfloat4*)x, beta_raw, (vfloat4*)out, bn4);
}

// Round 4
// 462.716 us; speedup vs baseline: 1.0261x; 1.0261x over previous
//
#include <hip/hip_runtime.h>

// PLIF forward scan: v = beta*v + x_t; s = (v-1 >= 0); v *= (1-s)
// T=32 sequential in registers; B*N lanes fully parallel.
//
// R1: simple loop, VGPR=28, 170us, 2.8 TB/s — one load in flight, every use
//     waits vmcnt(0) which (FIFO!) also drains prior stores.
// R3: PF=4 ring + NT stores: compiler collapsed ring (VGPR=20) and NT stores
//     made vmcnt(0) drain to HBM instead of L2 -> 205us. Reverted NT.
// R4: double-buffered chunk-8 register pipeline. 8 loads issued as one
//     cluster while the previous 8 steps compute+store; consumer waits with
//     vmcnt slack instead of vmcnt(0). __launch_bounds__(256,4) gives the
//     allocator a 128-VGPR budget so it can't fold the buffers.

#define T_STEPS 32
#define CH 8  // chunk depth (must divide T_STEPS)

typedef float vfloat4 __attribute__((ext_vector_type(4)));

__global__ __launch_bounds__(256, 4) void plif_fwd_kernel(
    const vfloat4* __restrict__ x, const float* __restrict__ beta_raw,
    vfloat4* __restrict__ out, int bn4)
{
    int i = blockIdx.x * blockDim.x + threadIdx.x;
    if (i >= bn4) return;

    // beta = sigmoid(beta_raw); precise expf to match reference trajectory
    float beta = 1.0f / (1.0f + expf(-beta_raw[0]));

    vfloat4 v = (vfloat4)(0.0f, 0.0f, 0.0f, 0.0f);

    // Prime: first chunk's 8 loads issued back-to-back.
    vfloat4 xa[CH], xb[CH];
    #pragma unroll
    for (int k = 0; k < CH; ++k) xa[k] = x[i + k * bn4];

    #pragma unroll
    for (int tc = 0; tc < T_STEPS; tc += CH) {
        // Issue next chunk's loads as one cluster BEFORE consuming this one:
        // they stay in flight through the 8 compute+store steps below.
        if (tc + CH < T_STEPS) {
            #pragma unroll
            for (int k = 0; k < CH; ++k) xb[k] = x[i + (tc + CH + k) * bn4];
        }

        #pragma unroll
        for (int k = 0; k < CH; ++k) {
            vfloat4 xt = xa[k];
            vfloat4 s;
            #pragma unroll
            for (int c = 0; c < 4; ++c) {
                // v = beta*v + x_t -- separate mul/add rounding (no fma
                // contraction), matching XLA's non-contracted mul+add.
                v[c] = __fadd_rn(__fmul_rn(beta, v[c]), xt[c]);
                // s = Heaviside(v - 1), reference op order: (v - one) >= 0
                s[c] = (__fadd_rn(v[c], -1.0f) >= 0.0f) ? 1.0f : 0.0f;
                // hard reset: v = v * (1 - s); exact since s in {0,1}
                v[c] *= (1.0f - s[c]);
            }
            out[i + (tc + k) * bn4] = s;
        }

        // Rotate buffers (register moves, coalesced by the compiler).
        #pragma unroll
        for (int k = 0; k < CH; ++k) xa[k] = xb[k];
    }
}

extern "C" void kernel_launch(void* const* d_in, const int* in_sizes, int n_in,
                              void* d_out, int out_size, void* d_ws, size_t ws_size,
                              hipStream_t stream) {
    const float* x        = (const float*)d_in[0];
    const float* beta_raw = (const float*)d_in[1];
    float* out            = (float*)d_out;

    int total = in_sizes[0];        // T*B*N = 67,108,864
    int bn    = total / T_STEPS;    // B*N   =  2,097,152
    int bn4   = bn / 4;             // float4 lanes = 524,288

    dim3 block(256);
    dim3 grid((bn4 + block.x - 1) / block.x);
    plif_fwd_kernel<<<grid, block, 0, stream>>>(
        (const vfloat4*)x, beta_raw, (vfloat4*)out, bn4);
}

// Round 5
// 456.081 us; speedup vs baseline: 1.0410x; 1.0145x over previous
//
#include <hip/hip_runtime.h>

// PLIF forward scan: v = beta*v + x_t; s = (v-1 >= 0); v *= (1-s)
// T=32 sequential in registers; B*N lanes fully parallel.
//
// R1: simple loop, VGPR=28, ~170us, 2.8 TB/s — 1 load in flight/wave.
// R3: PF=4 ring + NT stores: ring collapsed (VGPR=20), NT stores made every
//     vmcnt(0) drain to HBM -> 205us.
// R4: chunk-8 double buffer in plain C++: scheduler sank the loads again
//     (VGPR=36), 164us. Harness's own fillBuffer hits 6.5 TB/s => BW exists;
//     we are purely latency/MLP-bound and the compiler won't keep loads hoisted.
// R5: inline-asm global_load_dwordx4 (volatile => cannot be sunk) + manual
//     s_waitcnt vmcnt(8) + value fences. Two 8-deep buffers, alternating;
//     every chunk keeps 8 KB/wave of loads in flight through compute.
//     vmcnt retires in order, so vmcnt(8) == "everything older than the 8
//     loads just issued has retired" — exactly the consumed chunk + old stores.

#define T_STEPS 32
#define CH 8

typedef float vfloat4 __attribute__((ext_vector_type(4)));

// Issue CH independent 16B loads into buf (volatile: pinned in program order).
#define ISSUE(buf, tc)                                                        \
    _Pragma("unroll")                                                         \
    for (int k = 0; k < CH; ++k) {                                            \
        unsigned voff = base16 + (unsigned)((tc) + k) * stride16;             \
        asm volatile("global_load_dwordx4 %0, %1, %2"                        \
                     : "=v"(buf[k])                                           \
                     : "v"(voff), "s"(xp));                                   \
    }

// Wait until only the 8 newest VMEM ops remain outstanding.
#define WAIT8 asm volatile("s_waitcnt vmcnt(8)" ::: "memory")

// Data-dependency fence: consumers of buf must read the post-wait value,
// so they cannot be hoisted above WAIT8.
#define FENCE(buf)                                                            \
    _Pragma("unroll")                                                         \
    for (int k = 0; k < CH; ++k) asm volatile("" : "+v"(buf[k]));

#define CONSUME(buf, tc)                                                      \
    _Pragma("unroll")                                                         \
    for (int k = 0; k < CH; ++k) {                                            \
        vfloat4 xt = buf[k];                                                  \
        vfloat4 s;                                                            \
        _Pragma("unroll")                                                     \
        for (int c = 0; c < 4; ++c) {                                         \
            /* separate mul/add rounding: matches XLA non-contracted HLO */   \
            v[c] = __fadd_rn(__fmul_rn(beta, v[c]), xt[c]);                   \
            /* s = Heaviside(v - 1), reference op order */                    \
            s[c] = (__fadd_rn(v[c], -1.0f) >= 0.0f) ? 1.0f : 0.0f;            \
            /* hard reset, exact since s in {0,1} */                          \
            v[c] *= (1.0f - s[c]);                                            \
        }                                                                     \
        out[i + ((tc) + k) * bn4] = s;                                        \
    }

__global__ __launch_bounds__(256, 4) void plif_fwd_kernel(
    const vfloat4* __restrict__ xp, const float* __restrict__ beta_raw,
    vfloat4* __restrict__ out, int bn4)
{
    int i = blockIdx.x * blockDim.x + threadIdx.x;
    if (i >= bn4) return;

    // beta = sigmoid(beta_raw); precise expf matches reference trajectory.
    float beta = 1.0f / (1.0f + expf(-beta_raw[0]));
    // Pin beta's computation (and any load it needs) BEFORE the first ISSUE,
    // so no compiler-inserted wait lands in the middle of our pipeline.
    asm volatile("" : "+v"(beta));

    unsigned base16   = (unsigned)i * 16u;        // byte offset of lane, <4GB
    unsigned stride16 = (unsigned)bn4 * 16u;      // byte stride per t-step

    vfloat4 v = (vfloat4)(0.0f, 0.0f, 0.0f, 0.0f);
    vfloat4 A[CH], B[CH];

    ISSUE(A, 0);                       // queue: A(8)
    ISSUE(B, 8);                       // queue: A(8) B(8)
    WAIT8; FENCE(A); CONSUME(A, 0);    // retires A; stores S0 join queue
    ISSUE(A, 16);                      // queue: B,S0,A'
    WAIT8; FENCE(B); CONSUME(B, 8);    // retires B,S0; keeps A' in flight
    ISSUE(B, 24);                      // queue: A',S1,B'
    WAIT8; FENCE(A); CONSUME(A, 16);   // retires A',S1; keeps B' in flight
    WAIT8; FENCE(B); CONSUME(B, 24);   // retires B'; S2 may remain in flight
}

extern "C" void kernel_launch(void* const* d_in, const int* in_sizes, int n_in,
                              void* d_out, int out_size, void* d_ws, size_t ws_size,
                              hipStream_t stream) {
    const float* x        = (const float*)d_in[0];
    const float* beta_raw = (const float*)d_in[1];
    float* out            = (float*)d_out;

    int total = in_sizes[0];        // T*B*N = 67,108,864
    int bn    = total / T_STEPS;    // B*N   =  2,097,152
    int bn4   = bn / 4;             // float4 lanes = 524,288

    dim3 block(256);
    dim3 grid((bn4 + block.x - 1) / block.x);
    plif_fwd_kernel<<<grid, block, 0, stream>>>(
        (const vfloat4*)x, beta_raw, (vfloat4*)out, bn4);
}